// Round 4
// baseline (455.943 us; speedup 1.0000x reference)
//
#include <hip/hip_runtime.h>

// RMSNorm (fp32 accum) + dynamic per-token int8 quantization.
// Inputs arrive as FLOAT32 (harness widens the reference's fp16).
// d_out FLOAT32 flat: q-values [rows*H] then per-row scale [rows].
//
// R4: each block handles RPB=8 rows; w cached in registers (16 floats/thread,
// loaded once); double-buffered LDS combine -> 1 barrier/row; nontemporal
// q stores (write-once data, keep L2 for the input stream).
// q = round(xn/scale) = round(p * 127/max|p|) — the rsqrt cancels exactly.

#define HDIM  4096
#define BLOCK 256
#define RPB   8                // rows per block

typedef float v4f __attribute__((ext_vector_type(4)));

__global__ __launch_bounds__(BLOCK) void qrms_kernel(
    const float* __restrict__ x,
    const float* __restrict__ w,
    float* __restrict__ qout,
    float* __restrict__ sout)
{
    const int t = threadIdx.x;

    // cache w: 4 chunks of 1024 floats, 4 consecutive per thread
    float4 wv[4];
    #pragma unroll
    for (int c = 0; c < 4; ++c)
        wv[c] = *reinterpret_cast<const float4*>(w + c * (HDIM / 4) + t * 4);

    __shared__ float s_sum[2][4];
    __shared__ float s_max[2][4];
    const int wave = t >> 6;

    const size_t row0 = (size_t)blockIdx.x * RPB;
    #pragma unroll 1
    for (int rr = 0; rr < RPB; ++rr) {
        const size_t row = row0 + rr;
        const float* xr = x + row * HDIM;

        float p[16];
        float sumsq = 0.0f;
        float amax  = 0.0f;

        #pragma unroll
        for (int c = 0; c < 4; ++c) {
            const int idx = c * (HDIM / 4) + t * 4;
            const float4 xv = *reinterpret_cast<const float4*>(xr + idx);
            sumsq = fmaf(xv.x, xv.x, sumsq);
            sumsq = fmaf(xv.y, xv.y, sumsq);
            sumsq = fmaf(xv.z, xv.z, sumsq);
            sumsq = fmaf(xv.w, xv.w, sumsq);
            const float p0 = xv.x * wv[c].x;
            const float p1 = xv.y * wv[c].y;
            const float p2 = xv.z * wv[c].z;
            const float p3 = xv.w * wv[c].w;
            p[c * 4 + 0] = p0;
            p[c * 4 + 1] = p1;
            p[c * 4 + 2] = p2;
            p[c * 4 + 3] = p3;
            amax = fmaxf(amax, fmaxf(fmaxf(fabsf(p0), fabsf(p1)),
                                     fmaxf(fabsf(p2), fabsf(p3))));
        }

        // wave-64 butterfly reduction (sum + max together)
        #pragma unroll
        for (int off = 32; off > 0; off >>= 1) {
            sumsq += __shfl_xor(sumsq, off, 64);
            amax   = fmaxf(amax, __shfl_xor(amax, off, 64));
        }

        const int b = rr & 1;  // double-buffer: safe with a single barrier/row
        if ((t & 63) == 0) { s_sum[b][wave] = sumsq; s_max[b][wave] = amax; }
        __syncthreads();
        const float total = (s_sum[b][0] + s_sum[b][1]) + (s_sum[b][2] + s_sum[b][3]);
        const float mx    = fmaxf(fmaxf(s_max[b][0], s_max[b][1]),
                                  fmaxf(s_max[b][2], s_max[b][3]));

        const float r    = rsqrtf(total * (1.0f / HDIM) + 1e-6f);
        const float qmul = 127.0f / mx;            // p*qmul == xn/scale up to ulps

        if (t == 0) sout[row] = (mx * r) * (1.0f / 127.0f);   // max|xn|/127

        float* qr = qout + row * HDIM;
        #pragma unroll
        for (int c = 0; c < 4; ++c) {
            const int idx = c * (HDIM / 4) + t * 4;
            float q[4];
            #pragma unroll
            for (int k = 0; k < 4; ++k) {
                float v = rintf(p[c * 4 + k] * qmul);
                q[k] = fminf(127.0f, fmaxf(-128.0f, v));
            }
            v4f qv = { q[0], q[1], q[2], q[3] };
            __builtin_nontemporal_store(qv, reinterpret_cast<v4f*>(qr + idx));
        }
    }
}

extern "C" void kernel_launch(void* const* d_in, const int* in_sizes, int n_in,
                              void* d_out, int out_size, void* d_ws, size_t ws_size,
                              hipStream_t stream) {
    const float* x = (const float*)d_in[0];
    const float* w = (const float*)d_in[1];
    float* out = (float*)d_out;
    const int rows = in_sizes[0] / HDIM;           // B*S = 16384
    float* qout = out;
    float* sout = out + (size_t)in_sizes[0];       // scales after the q block
    qrms_kernel<<<dim3(rows / RPB), dim3(BLOCK), 0, stream>>>(x, w, qout, sout);
}